// Round 4
// baseline (3120.354 us; speedup 1.0000x reference)
//
#include <hip/hip_runtime.h>
#include <stdint.h>

// LSTM: B=256, T=1024, I=64, H=256, O=1. fp32 in/out, bf16 MFMA internally.
//
// Round-15: minimize the per-step synchronization graph. R14 proved traffic
// is irrelevant (WRITE 9.7GB->0.26GB yet slower); the cost is dependent
// fabric hops x wait fan-in x barrier count. New topology: 64 blocks = 32
// groups x 2 HALVES (H split 128/128). Each 512-thread block holds the
// weights for all 4 gates of its 128 hidden units register-resident
// (wf[4][10] = 160 VGPRs; ~225 total, __launch_bounds__(512,2) caps at 256
// so 8 waves co-reside on one CU).
//   - ONE peer per block: thread i polls exactly peer unit i (512<->512,
//     coalesced, balanced). Max-of-1 publish jitter (R14 had max-of-3).
//   - NO gate exchange: wave wv computes gates i,f,g,o (j=0..3) of the SAME
//     16 hidden units (hid = half*128+wv*16+ln), so all 4 gate values for a
//     (batch,hid) sit in one lane's acc[0..3] -> c/h update fully
//     in-register (c_reg floatx4, m=lk*4+r for lk<2). No xch LDS, no S2.
//   - ONE barrier/step via double-buffered h_lds[2][8][264]: iter t reads
//     buf[t&1], writes own half + next captures to buf[(t+1)&1]. Hazards:
//     reads(t) vs capture(t) same buf -> ordered by B(t); own-writes(t-1)
//     same buf -> before B(t) in program order; own-writes(t)/capture(t+1)
//     target the OTHER buf -> disjoint. All safe with a single barrier.
//   - publish fires immediately after h is computed (agent store, then LDS
//     write), so peer-visible latency starts ASAP.
// Communication primitive: R11-verified relaxed AGENT-scope (MALL) 8B
// loads/stores. Unit = {2xbf16 h pair, tag=step}. Quiet pipelined poll
// (R8/R10: hot polling congests fabric): first probe pre-sleep, reload
// issued BEFORE s_sleep(1) so MALL latency hides under it, satisfied lanes
// stop loading, SENT_CAP dead-latch => wrong-answer-not-hang.
//
// Parity/staleness safety (re-derived for 2 blocks): tag-t units (parity
// t&1) are overwritten by tag t+2 only after the writer's poll(t+1), which
// needs the peer's publish(t+1), which follows the peer's poll(t) =>
// no consumer can still need tag t. Cross-run: parity-1 last held 1023,
// parity-0 1022, poison 0xAAAAAAAA; poll(t) matches only exact t, and every
// same-parity publish (1,3,../2,4,..) overwrites all peer units first =>
// stale 1022/1023 cannot survive to polls 1022/1023. Final h (tag 1024)
// goes to a separate never-polled clean region at 2*UPP (R13-verified).
//
// Unit index in group: half*512 + m*64 + pair, pair = (hid - half*128)/2.

#define T_ 1024
#define I_ 64
#define H_ 256
#define NGROUP 32
#define MB 8      /* batches per group  */
#define HH 128    /* hidden units per block (half) */
#define HROW 264  /* padded h_lds row (ushorts), 528 B = 33 x 16 B */

#define UNITS_PER_GROUP 1024                       /* 8B units per step */
#define UNITS_PER_PARITY (NGROUP * UNITS_PER_GROUP)
#define SENT_CAP (1 << 16)   /* dead-latch: ~64k sleep-sweeps */

typedef float floatx4 __attribute__((ext_vector_type(4)));
typedef __bf16 bf16x8 __attribute__((ext_vector_type(8)));
typedef unsigned short ushortx8 __attribute__((ext_vector_type(8)));
typedef unsigned int uint32;
typedef unsigned long long u64;

__device__ __forceinline__ float bf2f(uint32 u16) {
  uint32 u = u16 << 16;
  return __builtin_bit_cast(float, u);
}
__device__ __forceinline__ bf16x8 packbf8(floatx4 a, floatx4 b) {
  bf16x8 r;
  r[0] = (__bf16)a[0]; r[1] = (__bf16)a[1];
  r[2] = (__bf16)a[2]; r[3] = (__bf16)a[3];
  r[4] = (__bf16)b[0]; r[5] = (__bf16)b[1];
  r[6] = (__bf16)b[2]; r[7] = (__bf16)b[3];
  return r;
}
__device__ __forceinline__ float fast_sig(float v) {
  return 1.0f / (1.0f + __expf(-v));
}
__device__ __forceinline__ float fast_tanh(float v) {
  float e = __expf(2.0f * v);
  return 1.0f - 2.0f / (e + 1.0f);
}
__device__ __forceinline__ u64 aload64(const u64* p) {
  return __hip_atomic_load(p, __ATOMIC_RELAXED, __HIP_MEMORY_SCOPE_AGENT);
}
__device__ __forceinline__ void astore64(u64* p, u64 v) {
  __hip_atomic_store(p, v, __ATOMIC_RELAXED, __HIP_MEMORY_SCOPE_AGENT);
}

__global__ __launch_bounds__(512, 2) void lstm_main(
    const float* __restrict__ x, const float* __restrict__ W_ih,
    const float* __restrict__ W_hh, const float* __restrict__ b_ih,
    const float* __restrict__ b_hh, u64* __restrict__ units) {
  const int tid = threadIdx.x;
  const int bid = blockIdx.x;
  const int half = bid >> 5;  // 0..1 (bid%8 == g%8 -> pair shares XCD rr)
  const int g = bid & 31;     // group 0..31
  const int wv = tid >> 6;    // wave 0..7 -> hid sub-block
  const int lane = tid & 63;
  const int ln = lane & 15;   // MFMA n (hid) / A row (batch, dup)
  const int lk = lane >> 4;   // MFMA k-subgroup / C row group

  __shared__ __align__(16) unsigned short h_lds[2][MB][HROW];

  const size_t gbase = (size_t)g * UNITS_PER_GROUP;
  const size_t obase = gbase + (size_t)half * 512;        // own units
  const size_t pbase = gbase + (size_t)(half ^ 1) * 512;  // peer units

  // zero both h_lds buffers (h_0 = 0; also clears pad)
  {
    uint32* p = (uint32*)&h_lds[0][0][0];
    for (int i = tid; i < 2 * MB * HROW / 2; i += 512) p[i] = 0u;
  }

  // ---- preload weight B-fragments (bf16) + bias, once ----
  // wave wv owns hid = half*128 + wv*16 + ln, ALL 4 gates (j).
  bf16x8 wf[4][10];
  float bias[4];
#pragma unroll
  for (int j = 0; j < 4; ++j) {
    const int row = j * 256 + half * HH + wv * 16 + ln;
    bias[j] = b_ih[row] + b_hh[row];
#pragma unroll
    for (int kc = 0; kc < 10; ++kc) {
      const int kk = kc * 32 + lk * 8;
      const float* src = (kk < I_) ? (W_ih + (size_t)row * I_ + kk)
                                   : (W_hh + (size_t)row * H_ + (kk - I_));
      floatx4 f0 = *(const floatx4*)src;
      floatx4 f1 = *(const floatx4*)(src + 4);
      wf[j][kc] = packbf8(f0, f1);
    }
  }

  const int mb = ln & 7;                       // batch row (m>=8 duplicates)
  const float* xrow = x + ((size_t)(g * MB + mb)) * T_ * I_;
  // poll roles: thread i <-> peer unit i
  const int pm = tid >> 6;                     // batch of polled unit (==wv)
  const int pcol = (half ^ 1) * HH + 2 * (tid & 63);  // h_lds col (ushort)
  // publish roles: active lanes lk<2 && even ln; pair idx within half
  const int ppair = wv * 8 + (ln >> 1);
  const int ocol = half * HH + wv * 16 + ln;   // own h_lds col (ushort)

  floatx4 c_reg = (floatx4){0.f, 0.f, 0.f, 0.f};

  __syncthreads();

#pragma unroll 1
  for (int t = 0; t < T_; ++t) {
    // x loads issued first so they overlap the poll
    floatx4 xf0, xf1, xf2, xf3;
    {
      const float* src = xrow + t * I_ + lk * 8;
      xf0 = *(const floatx4*)(src);
      xf1 = *(const floatx4*)(src + 4);
      xf2 = *(const floatx4*)(src + 32);
      xf3 = *(const floatx4*)(src + 36);
    }

    if (t > 0) {
      u64* up = units + (size_t)(t & 1) * UNITS_PER_PARITY + pbase + tid;
      // pipelined quiet poll: reload issued BEFORE the sleep.
      u64 v = aload64(up);
      bool ok = ((uint32)(v >> 32) == (uint32)t);
      int it = 0;
      while (!__all(ok) && ++it < SENT_CAP) {
        u64 n = 0;
        if (!ok) n = aload64(up);
        __builtin_amdgcn_s_sleep(1);
        if (!ok) {
          v = n;
          ok = ((uint32)(v >> 32) == (uint32)t);
        }
      }
      // capture payload into current read-buffer (peer half)
      *(uint32*)&h_lds[t & 1][pm][pcol] = (uint32)v;
    }
    __syncthreads();  // B(t): h_lds[t&1] fully ready

    bf16x8 a0 = packbf8(xf0, xf1);
    bf16x8 a1 = packbf8(xf2, xf3);
    const unsigned short* hrow = &h_lds[t & 1][mb][0];

    // ---- MFMA: acc[j][m] = gate-j pre-activation, bias in acc ----
    floatx4 acc[4];
#pragma unroll
    for (int j = 0; j < 4; ++j)
      acc[j] = (floatx4){bias[j], bias[j], bias[j], bias[j]};
#pragma unroll
    for (int kc = 0; kc < 10; ++kc) {
      bf16x8 a;
      if (kc == 0) a = a0;
      else if (kc == 1) a = a1;
      else
        a = __builtin_bit_cast(
            bf16x8, *(const ushortx8*)(hrow + (kc - 2) * 32 + lk * 8));
#pragma unroll
      for (int j = 0; j < 4; ++j)
        acc[j] = __builtin_amdgcn_mfma_f32_16x16x32_bf16(a, wf[j][kc],
                                                         acc[j], 0, 0, 0);
    }

    // ---- in-register nonlinearity + c/h update (valid rows: lk<2) ----
    if (lk < 2) {
      floatx4 iv, fv, gv, ov;
#pragma unroll
      for (int r = 0; r < 4; ++r) {
        iv[r] = fast_sig(acc[0][r]);
        fv[r] = fast_sig(acc[1][r]);
        gv[r] = fast_tanh(acc[2][r]);
        ov[r] = fast_sig(acc[3][r]);
      }
      c_reg = fv * c_reg + iv * gv;
#pragma unroll
      for (int r = 0; r < 4; ++r) {
        float hv = ov[r] * fast_tanh(c_reg[r]);
        unsigned short hb = __builtin_bit_cast(unsigned short, (__bf16)hv);
        int pv = __shfl_xor((int)hb, 1);  // partner ln^1, same lk
        if ((ln & 1) == 0) {
          const int m = lk * 4 + r;
          uint32 dword = (uint32)hb | ((uint32)(unsigned short)pv << 16);
          u64 val = (u64)dword | ((u64)(uint32)(t + 1) << 32);
          const size_t uoff = obase + (size_t)m * 64 + ppair;
          if (t == T_ - 1) {
            // final h -> clean region (never polled, never RMW'd)
            astore64(units + 2 * (size_t)UNITS_PER_PARITY + uoff, val);
          } else {
            astore64(units + (size_t)((t + 1) & 1) * UNITS_PER_PARITY + uoff,
                     val);
            // own half -> next read-buffer
            *(uint32*)&h_lds[(t + 1) & 1][m][ocol] = dword;
          }
        }
      }
    }
  }
}

// out[b] = dot(h_T[b], fc_w) + fc_b. Final h lives in the clean region at
// offset 2*UPP. Agent loads -> fresh across replays, no flush dependency.
__global__ void lstm_fc(const u64* __restrict__ units,
                        const float* __restrict__ fc_w,
                        const float* __restrict__ fc_b,
                        float* __restrict__ out) {
  const int b = threadIdx.x;
  const int g = b >> 3, m = b & 7;
  const u64* base =
      units + 2 * (size_t)UNITS_PER_PARITY + (size_t)g * UNITS_PER_GROUP;
  float sum = fc_b[0];
#pragma unroll 4
  for (int u = 0; u < 128; ++u) {
    const int hf = u >> 6, pair = u & 63;
    u64 v = aload64(base + hf * 512 + m * 64 + pair);
    uint32 lo = (uint32)v;
    const int d = hf * HH + 2 * pair;
    sum += bf2f(lo & 0xffffu) * fc_w[d] + bf2f(lo >> 16) * fc_w[d + 1];
  }
  out[b] = sum;
}

extern "C" void kernel_launch(void* const* d_in, const int* in_sizes, int n_in,
                              void* d_out, int out_size, void* d_ws,
                              size_t ws_size, hipStream_t stream) {
  const float* x    = (const float*)d_in[0];
  const float* W_ih = (const float*)d_in[1];
  const float* W_hh = (const float*)d_in[2];
  const float* b_ih = (const float*)d_in[3];
  const float* b_hh = (const float*)d_in[4];
  const float* fc_w = (const float*)d_in[5];
  const float* fc_b = (const float*)d_in[6];
  float* out = (float*)d_out;

  u64* units = (u64*)d_ws;  // 2 parities + final region: 3*256KB = 768KB ws
  // tag poison 0xAAAAAAAA != any live tag (1..1024) => no init needed.

  lstm_main<<<dim3(NGROUP * 2), dim3(512), 0, stream>>>(
      x, W_ih, W_hh, b_ih, b_hh, units);
  lstm_fc<<<dim3(1), dim3(256), 0, stream>>>(units, fc_w, fc_b, out);
}